// Round 2
// baseline (1718.369 us; speedup 1.0000x reference)
//
#include <hip/hip_runtime.h>
#include <cstdint>
#include <cstddef>

#define N_ATOMS 10000
#define NSTRUCT 100
#define NP 4
#define NS 4
#define NQ 32
#define NFEAT 4096
#define HID 256

__device__ __forceinline__ float silu(float x) {
  return x / (1.f + __expf(-x));
}

// ---------------- Kernel A: power-spectrum features ----------------
// feat[a, l*1024 + q*32 + r] = (1/sqrt(2l+1)) * sum_m c_l[a,m,q]*c_l[a,m,r]
__global__ __launch_bounds__(256) void feat_kernel(
    const float* __restrict__ c0, const float* __restrict__ c1,
    const float* __restrict__ c2, const float* __restrict__ c3,
    float* __restrict__ feat) {
  int a = blockIdx.x;
  __shared__ float cs[512];
  int tid = threadIdx.x;
  for (int e = tid; e < 512; e += 256) {
    float v;
    if (e < 32)       v = c0[a * 32  + e];
    else if (e < 128) v = c1[a * 96  + (e - 32)];
    else if (e < 288) v = c2[a * 160 + (e - 128)];
    else              v = c3[a * 224 + (e - 288)];
    cs[e] = v;
  }
  __syncthreads();
  const float cg[4]  = {1.0f, 0.5773502691896258f, 0.4472135954999579f, 0.3779644730092272f};
  const int  off[4]  = {0, 32, 128, 288};
  const int  nm[4]   = {1, 3, 5, 7};
  for (int f = tid; f < NFEAT; f += 256) {
    int l = f >> 10;
    int rem = f & 1023;
    int q = rem >> 5, r = rem & 31;
    const float* base = cs + off[l];
    float s = 0.f;
    for (int m = 0; m < nm[l]; ++m) s += base[m * 32 + q] * base[m * 32 + r];
    feat[(size_t)a * NFEAT + f] = s * cg[l];
  }
}

// ---------------- Kernel B: big GEMM + pw scale + silu ----------------
// h0[a, p*256+h] = silu( pw[a,p] * sum_f feat[a,f] * W0[p,f,h] )
// Tiles: BM=64, BN=64, BK=16; 256 threads, 4x4 microtile.
__global__ __launch_bounds__(256) void gemm0_kernel(
    const float* __restrict__ feat, const float* __restrict__ W0,
    const float* __restrict__ combW, const int* __restrict__ species,
    float* __restrict__ h0) {
  __shared__ float As[16][65];   // [k][m], padded
  __shared__ float Bs[16][64];   // [k][n]
  int bn = blockIdx.x * 64;      // global n in [0,1024)
  int bm = blockIdx.y * 64;      // atom base
  int tid = threadIdx.x;
  int tx = tid & 15, ty = tid >> 4;
  int p  = bn >> 8;              // BN=64 tiles never straddle p boundaries
  const float* W0p = W0 + (size_t)p * NFEAT * HID;
  int hn = bn & 255;             // h base within this p
  float acc[4][4] = {};
  for (int k0 = 0; k0 < NFEAT; k0 += 16) {
#pragma unroll
    for (int i = 0; i < 4; ++i) {
      int e = tid + i * 256;
      int row = e >> 4, col = e & 15;
      int a = bm + row;
      As[col][row] = (a < N_ATOMS) ? feat[(size_t)a * NFEAT + k0 + col] : 0.f;
    }
#pragma unroll
    for (int i = 0; i < 4; ++i) {
      int e = tid + i * 256;
      int k = e >> 6, n = e & 63;
      Bs[k][n] = W0p[(size_t)(k0 + k) * HID + hn + n];
    }
    __syncthreads();
#pragma unroll
    for (int k = 0; k < 16; ++k) {
      float af[4], bf[4];
#pragma unroll
      for (int i = 0; i < 4; ++i) af[i] = As[k][ty * 4 + i];
#pragma unroll
      for (int j = 0; j < 4; ++j) bf[j] = Bs[k][tx * 4 + j];
#pragma unroll
      for (int i = 0; i < 4; ++i)
#pragma unroll
        for (int j = 0; j < 4; ++j)
          acc[i][j] += af[i] * bf[j];
    }
    __syncthreads();
  }
#pragma unroll
  for (int i = 0; i < 4; ++i) {
    int a = bm + ty * 4 + i;
    if (a >= N_ATOMS) continue;
    float pw = combW[p * NS + species[a]];
#pragma unroll
    for (int j = 0; j < 4; ++j) {
      float v = pw * acc[i][j];
      h0[(size_t)a * 1024 + bn + tx * 4 + j] = silu(v);
    }
  }
}

// ---------------- Kernel C: layer1 GEMM + silu + layer2 dot + segment-sum ----
// Block: 32 atoms x one p. 256 thr = 4 waves; wave w owns atoms [w*8, w*8+8),
// lane ht in [0,64) owns h = ht*4..ht*4+3. LDS holds h0 tile transposed [k][ai].
__global__ __launch_bounds__(256) void mlp_kernel(
    const float* __restrict__ h0, const float* __restrict__ W1,
    const float* __restrict__ W2, const int* __restrict__ sid,
    float* __restrict__ out) {
  int p  = blockIdx.y;
  int a0 = blockIdx.x * 32;
  int tid = threadIdx.x;
  __shared__ float hs[256 * 33];   // hs[k*33 + ai]
  for (int ai = 0; ai < 32; ++ai) {
    int a = a0 + ai;
    float v = (a < N_ATOMS) ? h0[(size_t)a * 1024 + p * 256 + tid] : 0.f;
    hs[tid * 33 + ai] = v;   // bank = (tid+ai)%32: conflict-free
  }
  __syncthreads();
  int ht  = tid & 63;
  int wv  = tid >> 6;
  int ai0 = wv * 8;
  const float* W1p = W1 + p * (HID * HID);
  float acc[8][4];
#pragma unroll
  for (int i = 0; i < 8; ++i)
#pragma unroll
    for (int j = 0; j < 4; ++j) acc[i][j] = 0.f;
  for (int k = 0; k < 256; ++k) {
    float4 w = *reinterpret_cast<const float4*>(&W1p[k * 256 + ht * 4]);
    float av[8];
#pragma unroll
    for (int i = 0; i < 8; ++i) av[i] = hs[k * 33 + ai0 + i];  // wave-broadcast
#pragma unroll
    for (int i = 0; i < 8; ++i) {
      acc[i][0] += av[i] * w.x;
      acc[i][1] += av[i] * w.y;
      acc[i][2] += av[i] * w.z;
      acc[i][3] += av[i] * w.w;
    }
  }
  float4 w2 = *reinterpret_cast<const float4*>(&W2[p * 256 + ht * 4]);
#pragma unroll
  for (int i = 0; i < 8; ++i) {
    float v = silu(acc[i][0]) * w2.x + silu(acc[i][1]) * w2.y +
              silu(acc[i][2]) * w2.z + silu(acc[i][3]) * w2.w;
#pragma unroll
    for (int off = 32; off > 0; off >>= 1) v += __shfl_xor(v, off, 64);
    if (ht == 0) {
      int a = a0 + ai0 + i;
      if (a < N_ATOMS) atomicAdd(&out[sid[a]], v);
    }
  }
}

extern "C" void kernel_launch(void* const* d_in, const int* in_sizes, int n_in,
                              void* d_out, int out_size, void* d_ws, size_t ws_size,
                              hipStream_t stream) {
  const float* c0      = (const float*)d_in[0];
  const float* c1      = (const float*)d_in[1];
  const float* c2      = (const float*)d_in[2];
  const float* c3      = (const float*)d_in[3];
  const int*   species = (const int*)d_in[4];
  const int*   sid     = (const int*)d_in[5];
  const float* combW   = (const float*)d_in[6];
  const float* W0      = (const float*)d_in[7];
  const float* W1      = (const float*)d_in[8];
  const float* W2      = (const float*)d_in[9];
  float*       out     = (float*)d_out;

  float* feat = (float*)d_ws;                          // 10000*4096 floats = 163.84 MB
  float* h0   = feat + (size_t)N_ATOMS * NFEAT;        // 10000*1024 floats =  40.96 MB

  (void)hipMemsetAsync(d_out, 0, (size_t)out_size * sizeof(float), stream);

  feat_kernel<<<N_ATOMS, 256, 0, stream>>>(c0, c1, c2, c3, feat);

  dim3 g2(16, 157);   // 1024/64 n-tiles, ceil(10000/64) m-tiles
  gemm0_kernel<<<g2, 256, 0, stream>>>(feat, W0, combW, species, h0);

  dim3 g3(313, 4);    // ceil(10000/32) atom-tiles x P
  mlp_kernel<<<g3, 256, 0, stream>>>(h0, W1, W2, sid, out);
}

// Round 3
// 721.109 us; speedup vs baseline: 2.3830x; 2.3830x over previous
//
#include <hip/hip_runtime.h>
#include <hip/hip_bf16.h>
#include <cstdint>
#include <cstddef>

#define N_ATOMS 10000
#define NSTRUCT 100
#define NP 4
#define NS 4
#define NFEAT 4096
#define HID 256
#define APAD 10112   // 79 tiles of 128

typedef __attribute__((ext_vector_type(8))) short bf16x8;
typedef __attribute__((ext_vector_type(4))) float f32x4;

__device__ __forceinline__ float silu(float x) {
  return x / (1.f + __expf(-x));
}
__device__ __forceinline__ ushort f2bf(float x) {
  __hip_bfloat16 b = __float2bfloat16(x);
  return *reinterpret_cast<ushort*>(&b);
}
__device__ __forceinline__ float bf2f(ushort u) {
  __hip_bfloat16 b = *reinterpret_cast<__hip_bfloat16*>(&u);
  return __bfloat162float(b);
}

typedef __attribute__((address_space(3))) uint32_t lds_u32;
typedef const __attribute__((address_space(1))) uint32_t glb_u32;
__device__ __forceinline__ void glds16(const ushort* g, ushort* l) {
  __builtin_amdgcn_global_load_lds((glb_u32*)g, (lds_u32*)l, 16, 0, 0);
}

// ---------------- Kernel A: power spectrum -> bf16 hi/lo ----------------
__global__ __launch_bounds__(256) void feat_kernel(
    const float* __restrict__ c0, const float* __restrict__ c1,
    const float* __restrict__ c2, const float* __restrict__ c3,
    ushort* __restrict__ fhi, ushort* __restrict__ flo) {
  int a = blockIdx.x;
  __shared__ float cs[512];
  int tid = threadIdx.x;
  for (int e = tid; e < 512; e += 256) {
    float v;
    if (e < 32)       v = c0[a * 32  + e];
    else if (e < 128) v = c1[a * 96  + (e - 32)];
    else if (e < 288) v = c2[a * 160 + (e - 128)];
    else              v = c3[a * 224 + (e - 288)];
    cs[e] = v;
  }
  __syncthreads();
  const float cg[4]  = {1.0f, 0.5773502691896258f, 0.4472135954999579f, 0.3779644730092272f};
  const int  off[4]  = {0, 32, 128, 288};
  const int  nm[4]   = {1, 3, 5, 7};
  for (int f = tid; f < NFEAT; f += 256) {
    int l = f >> 10;
    int rem = f & 1023;
    int q = rem >> 5, r = rem & 31;
    const float* base = cs + off[l];
    float s = 0.f;
    for (int m = 0; m < nm[l]; ++m) s += base[m * 32 + q] * base[m * 32 + r];
    s *= cg[l];
    ushort hi = f2bf(s);
    ushort lo = f2bf(s - bf2f(hi));
    fhi[(size_t)a * NFEAT + f] = hi;
    flo[(size_t)a * NFEAT + f] = lo;
  }
}

// ---------------- Kernel A2: W0 [p][k][n] fp32 -> W0t [p][n][k] bf16 --------
__global__ __launch_bounds__(256) void w0cvt_kernel(
    const float* __restrict__ W0, ushort* __restrict__ W0t) {
  __shared__ float t[32][33];
  int p = blockIdx.z;
  int kt = blockIdx.y * 32, nt = blockIdx.x * 32;
  int lx = threadIdx.x & 31, ly = threadIdx.x >> 5;
  const float* src = W0 + (size_t)p * NFEAT * HID;
#pragma unroll
  for (int i = 0; i < 4; ++i) {
    int k = kt + ly + i * 8;
    t[ly + i * 8][lx] = src[(size_t)k * HID + nt + lx];
  }
  __syncthreads();
  ushort* dst = W0t + (size_t)p * HID * NFEAT;
#pragma unroll
  for (int i = 0; i < 4; ++i) {
    int n = nt + ly + i * 8;
    dst[(size_t)n * NFEAT + kt + lx] = f2bf(t[lx][ly + i * 8]);
  }
}

// ---------------- Kernel B: MFMA GEMM, split-A 2-pass, fused pw*silu --------
// C[a, n=p*256+h] ; A = feat (hi+lo) [a][k] ; B = W0t [n][k]
// 128x128 tile, BK=32, 4 waves in 2x2, each wave 64x64 via 4x4 16x16 subtiles.
__global__ __launch_bounds__(256) void gemm0_mfma(
    const ushort* __restrict__ fhi, const ushort* __restrict__ flo,
    const ushort* __restrict__ W0t, const float* __restrict__ combW,
    const int* __restrict__ species, float* __restrict__ h0) {
  __shared__ ushort Ah[128 * 32];   // [m][k] 64B rows, 8KB
  __shared__ ushort Al[128 * 32];
  __shared__ ushort Bs[128 * 32];   // [n][k]
  int tid = threadIdx.x;
  int bm = blockIdx.y * 128;
  int bn = blockIdx.x * 128;
  int wid = tid >> 6, lane = tid & 63;
  int wm = (wid >> 1) * 64, wn = (wid & 1) * 64;

  // staging addresses: thread covers (row = tid>>2, 16B chunk = tid&3)
  int srow = tid >> 2, skp = tid & 3;
  const ushort* ga_hi = fhi + ((size_t)(bm + srow) * NFEAT + skp * 8);
  const ushort* ga_lo = flo + ((size_t)(bm + srow) * NFEAT + skp * 8);
  const ushort* gb    = W0t + ((size_t)(bn + srow) * NFEAT + skp * 8);
  ushort* lA = Ah + tid * 8;        // wave-uniform base + lane*16B
  ushort* lAl = Al + tid * 8;
  ushort* lB = Bs + tid * 8;
  const size_t half = (size_t)64 * NFEAT;

  f32x4 acc[4][4];
#pragma unroll
  for (int i = 0; i < 4; ++i)
#pragma unroll
    for (int j = 0; j < 4; ++j) acc[i][j] = (f32x4){0.f, 0.f, 0.f, 0.f};

  int mrow = lane & 15;
  int ksel = (lane >> 4) * 8;

  for (int k0 = 0; k0 < NFEAT; k0 += 32) {
    glds16(ga_hi + k0,        lA);
    glds16(ga_hi + k0 + half, lA + 2048);
    glds16(ga_lo + k0,        lAl);
    glds16(ga_lo + k0 + half, lAl + 2048);
    glds16(gb + k0,           lB);
    glds16(gb + k0 + half,    lB + 2048);
    __syncthreads();

    bf16x8 af_h[4], af_l[4], bfr[4];
#pragma unroll
    for (int i = 0; i < 4; ++i) {
      af_h[i] = *reinterpret_cast<const bf16x8*>(&Ah[(wm + i * 16 + mrow) * 32 + ksel]);
      af_l[i] = *reinterpret_cast<const bf16x8*>(&Al[(wm + i * 16 + mrow) * 32 + ksel]);
      bfr[i]  = *reinterpret_cast<const bf16x8*>(&Bs[(wn + i * 16 + mrow) * 32 + ksel]);
    }
#pragma unroll
    for (int i = 0; i < 4; ++i)
#pragma unroll
      for (int j = 0; j < 4; ++j) {
        acc[i][j] = __builtin_amdgcn_mfma_f32_16x16x32_bf16(af_h[i], bfr[j], acc[i][j], 0, 0, 0);
        acc[i][j] = __builtin_amdgcn_mfma_f32_16x16x32_bf16(af_l[i], bfr[j], acc[i][j], 0, 0, 0);
      }
    __syncthreads();
  }

  // epilogue: D row = (lane>>4)*4 + r, col = lane&15
  int p = bn >> 8;
  int col = lane & 15, rbase = (lane >> 4) * 4;
#pragma unroll
  for (int i = 0; i < 4; ++i) {
#pragma unroll
    for (int r = 0; r < 4; ++r) {
      int m = bm + wm + i * 16 + rbase + r;
      if (m >= N_ATOMS) continue;
      float pw = combW[p * NS + species[m]];
#pragma unroll
      for (int j = 0; j < 4; ++j) {
        int n = bn + wn + j * 16 + col;
        h0[(size_t)m * 1024 + n] = silu(pw * acc[i][j][r]);
      }
    }
  }
}

// ---------------- Kernel C: layer1 GEMM + silu + layer2 dot + segment-sum ----
__global__ __launch_bounds__(256) void mlp_kernel(
    const float* __restrict__ h0, const float* __restrict__ W1,
    const float* __restrict__ W2, const int* __restrict__ sid,
    float* __restrict__ out) {
  int p  = blockIdx.y;
  int a0 = blockIdx.x * 32;
  int tid = threadIdx.x;
  __shared__ float hs[256 * 33];
  for (int ai = 0; ai < 32; ++ai) {
    int a = a0 + ai;
    float v = (a < N_ATOMS) ? h0[(size_t)a * 1024 + p * 256 + tid] : 0.f;
    hs[tid * 33 + ai] = v;
  }
  __syncthreads();
  int ht  = tid & 63;
  int wv  = tid >> 6;
  int ai0 = wv * 8;
  const float* W1p = W1 + p * (HID * HID);
  float acc[8][4];
#pragma unroll
  for (int i = 0; i < 8; ++i)
#pragma unroll
    for (int j = 0; j < 4; ++j) acc[i][j] = 0.f;
  for (int k = 0; k < 256; ++k) {
    float4 w = *reinterpret_cast<const float4*>(&W1p[k * 256 + ht * 4]);
    float av[8];
#pragma unroll
    for (int i = 0; i < 8; ++i) av[i] = hs[k * 33 + ai0 + i];
#pragma unroll
    for (int i = 0; i < 8; ++i) {
      acc[i][0] += av[i] * w.x;
      acc[i][1] += av[i] * w.y;
      acc[i][2] += av[i] * w.z;
      acc[i][3] += av[i] * w.w;
    }
  }
  float4 w2 = *reinterpret_cast<const float4*>(&W2[p * 256 + ht * 4]);
#pragma unroll
  for (int i = 0; i < 8; ++i) {
    float v = silu(acc[i][0]) * w2.x + silu(acc[i][1]) * w2.y +
              silu(acc[i][2]) * w2.z + silu(acc[i][3]) * w2.w;
#pragma unroll
    for (int off = 32; off > 0; off >>= 1) v += __shfl_xor(v, off, 64);
    if (ht == 0) {
      int a = a0 + ai0 + i;
      if (a < N_ATOMS) atomicAdd(&out[sid[a]], v);
    }
  }
}

extern "C" void kernel_launch(void* const* d_in, const int* in_sizes, int n_in,
                              void* d_out, int out_size, void* d_ws, size_t ws_size,
                              hipStream_t stream) {
  const float* c0      = (const float*)d_in[0];
  const float* c1      = (const float*)d_in[1];
  const float* c2      = (const float*)d_in[2];
  const float* c3      = (const float*)d_in[3];
  const int*   species = (const int*)d_in[4];
  const int*   sid     = (const int*)d_in[5];
  const float* combW   = (const float*)d_in[6];
  const float* W0      = (const float*)d_in[7];
  const float* W1      = (const float*)d_in[8];
  const float* W2      = (const float*)d_in[9];
  float*       out     = (float*)d_out;

  // ws layout (bytes): fhi 82.8MB | flo 82.8MB | W0t 8.4MB | h0 41MB  = ~215MB
  ushort* fhi = (ushort*)d_ws;
  ushort* flo = fhi + (size_t)APAD * NFEAT;
  ushort* W0t = flo + (size_t)APAD * NFEAT;
  float*  h0  = (float*)(W0t + (size_t)NP * HID * NFEAT);

  (void)hipMemsetAsync(out, 0, (size_t)out_size * sizeof(float), stream);
  // zero the padded tail rows of fhi/flo (poisoned 0xAA otherwise)
  (void)hipMemsetAsync(fhi + (size_t)N_ATOMS * NFEAT, 0,
                       (size_t)(APAD - N_ATOMS) * NFEAT * sizeof(ushort), stream);
  (void)hipMemsetAsync(flo + (size_t)N_ATOMS * NFEAT, 0,
                       (size_t)(APAD - N_ATOMS) * NFEAT * sizeof(ushort), stream);

  feat_kernel<<<N_ATOMS, 256, 0, stream>>>(c0, c1, c2, c3, fhi, flo);

  dim3 gw(HID / 32, NFEAT / 32, NP);
  w0cvt_kernel<<<gw, 256, 0, stream>>>(W0, W0t);

  dim3 g2(1024 / 128, APAD / 128);   // 8 x 79
  gemm0_mfma<<<g2, 256, 0, stream>>>(fhi, flo, W0t, combW, species, h0);

  dim3 g3(313, 4);
  mlp_kernel<<<g3, 256, 0, stream>>>(h0, W1, W2, sid, out);
}

// Round 4
// 495.707 us; speedup vs baseline: 3.4665x; 1.4547x over previous
//
#include <hip/hip_runtime.h>
#include <hip/hip_bf16.h>
#include <cstdint>
#include <cstddef>

#define N_ATOMS 10000
#define NSTRUCT 100
#define NP 4
#define NS 4
#define NFEAT 4096
#define HID 256
#define APAD 10112   // 79 tiles of 128

typedef __attribute__((ext_vector_type(8))) _Float16 f16x8;
typedef __attribute__((ext_vector_type(4))) float f32x4;

__device__ __forceinline__ float silu(float x) {
  return x / (1.f + __expf(-x));
}
__device__ __forceinline__ ushort f2h(float x) {
  _Float16 h = (_Float16)x;
  return *reinterpret_cast<ushort*>(&h);
}

typedef __attribute__((address_space(3))) uint32_t lds_u32;
typedef const __attribute__((address_space(1))) uint32_t glb_u32;
__device__ __forceinline__ void glds16(const ushort* g, ushort* l) {
  __builtin_amdgcn_global_load_lds((glb_u32*)g, (lds_u32*)l, 16, 0, 0);
}

// ---------------- Kernel A: power spectrum -> fp16 ----------------
__global__ __launch_bounds__(256) void feat_kernel(
    const float* __restrict__ c0, const float* __restrict__ c1,
    const float* __restrict__ c2, const float* __restrict__ c3,
    ushort* __restrict__ fh) {
  int a = blockIdx.x;
  __shared__ float cs[512];
  int tid = threadIdx.x;
  for (int e = tid; e < 512; e += 256) {
    float v;
    if (e < 32)       v = c0[a * 32  + e];
    else if (e < 128) v = c1[a * 96  + (e - 32)];
    else if (e < 288) v = c2[a * 160 + (e - 128)];
    else              v = c3[a * 224 + (e - 288)];
    cs[e] = v;
  }
  __syncthreads();
  const float cg[4]  = {1.0f, 0.5773502691896258f, 0.4472135954999579f, 0.3779644730092272f};
  const int  off[4]  = {0, 32, 128, 288};
  const int  nm[4]   = {1, 3, 5, 7};
  for (int f = tid; f < NFEAT; f += 256) {
    int l = f >> 10;
    int rem = f & 1023;
    int q = rem >> 5, r = rem & 31;
    const float* base = cs + off[l];
    float s = 0.f;
    for (int m = 0; m < nm[l]; ++m) s += base[m * 32 + q] * base[m * 32 + r];
    fh[(size_t)a * NFEAT + f] = f2h(s * cg[l]);
  }
}

// ---------------- Kernel A2: W0 [p][k][n] fp32 -> W0t [p][n][k] fp16 --------
__global__ __launch_bounds__(256) void w0cvt_kernel(
    const float* __restrict__ W0, ushort* __restrict__ W0t) {
  __shared__ float t[32][33];
  int p = blockIdx.z;
  int kt = blockIdx.y * 32, nt = blockIdx.x * 32;
  int lx = threadIdx.x & 31, ly = threadIdx.x >> 5;
  const float* src = W0 + (size_t)p * NFEAT * HID;
#pragma unroll
  for (int i = 0; i < 4; ++i) {
    int k = kt + ly + i * 8;
    t[ly + i * 8][lx] = src[(size_t)k * HID + nt + lx];
  }
  __syncthreads();
  ushort* dst = W0t + (size_t)p * HID * NFEAT;
#pragma unroll
  for (int i = 0; i < 4; ++i) {
    int n = nt + ly + i * 8;
    dst[(size_t)n * NFEAT + kt + lx] = f2h(t[lx][ly + i * 8]);
  }
}

// ---------------- Kernel B: fp16 MFMA GEMM, fused pw*silu --------
// C[a, n=p*256+h] ; A = feat fp16 [a][k] ; B = W0t fp16 [n][k]
// 128x128 tile, BK=32, 4 waves 2x2, each wave 64x64 via 4x4 16x16x32 subtiles.
__global__ __launch_bounds__(256) void gemm0_mfma(
    const ushort* __restrict__ fh, const ushort* __restrict__ W0t,
    const float* __restrict__ combW, const int* __restrict__ species,
    float* __restrict__ h0) {
  __shared__ ushort As[128 * 32];   // [m][k] 64B rows, 8KB
  __shared__ ushort Bs[128 * 32];   // [n][k]
  int tid = threadIdx.x;
  int bm = blockIdx.y * 128;
  int bn = blockIdx.x * 128;
  int wid = tid >> 6, lane = tid & 63;
  int wm = (wid >> 1) * 64, wn = (wid & 1) * 64;

  int srow = tid >> 2, skp = tid & 3;
  const ushort* ga = fh  + ((size_t)(bm + srow) * NFEAT + skp * 8);
  const ushort* gb = W0t + ((size_t)(bn + srow) * NFEAT + skp * 8);
  ushort* lA = As + tid * 8;        // wave-uniform base + lane*16B
  ushort* lB = Bs + tid * 8;
  const size_t half = (size_t)64 * NFEAT;

  f32x4 acc[4][4];
#pragma unroll
  for (int i = 0; i < 4; ++i)
#pragma unroll
    for (int j = 0; j < 4; ++j) acc[i][j] = (f32x4){0.f, 0.f, 0.f, 0.f};

  int mrow = lane & 15;
  int ksel = (lane >> 4) * 8;

  for (int k0 = 0; k0 < NFEAT; k0 += 32) {
    glds16(ga + k0,        lA);
    glds16(ga + k0 + half, lA + 2048);
    glds16(gb + k0,        lB);
    glds16(gb + k0 + half, lB + 2048);
    __syncthreads();

    f16x8 af[4], bf[4];
#pragma unroll
    for (int i = 0; i < 4; ++i) {
      af[i] = *reinterpret_cast<const f16x8*>(&As[(wm + i * 16 + mrow) * 32 + ksel]);
      bf[i] = *reinterpret_cast<const f16x8*>(&Bs[(wn + i * 16 + mrow) * 32 + ksel]);
    }
#pragma unroll
    for (int i = 0; i < 4; ++i)
#pragma unroll
      for (int j = 0; j < 4; ++j)
        acc[i][j] = __builtin_amdgcn_mfma_f32_16x16x32_f16(af[i], bf[j], acc[i][j], 0, 0, 0);
    __syncthreads();
  }

  // epilogue: D row = (lane>>4)*4 + r, col = lane&15
  int p = bn >> 8;
  int col = lane & 15, rbase = (lane >> 4) * 4;
#pragma unroll
  for (int i = 0; i < 4; ++i) {
#pragma unroll
    for (int r = 0; r < 4; ++r) {
      int m = bm + wm + i * 16 + rbase + r;
      if (m >= N_ATOMS) continue;
      float pw = combW[p * NS + species[m]];
#pragma unroll
      for (int j = 0; j < 4; ++j) {
        int n = bn + wn + j * 16 + col;
        h0[(size_t)m * 1024 + n] = silu(pw * acc[i][j][r]);
      }
    }
  }
}

// ---------------- Kernel C: layer1 GEMM + silu + layer2 dot + segment-sum ----
__global__ __launch_bounds__(256) void mlp_kernel(
    const float* __restrict__ h0, const float* __restrict__ W1,
    const float* __restrict__ W2, const int* __restrict__ sid,
    float* __restrict__ out) {
  int p  = blockIdx.y;
  int a0 = blockIdx.x * 32;
  int tid = threadIdx.x;
  __shared__ float hs[256 * 33];
  for (int ai = 0; ai < 32; ++ai) {
    int a = a0 + ai;
    float v = (a < N_ATOMS) ? h0[(size_t)a * 1024 + p * 256 + tid] : 0.f;
    hs[tid * 33 + ai] = v;
  }
  __syncthreads();
  int ht  = tid & 63;
  int wv  = tid >> 6;
  int ai0 = wv * 8;
  const float* W1p = W1 + p * (HID * HID);
  float acc[8][4];
#pragma unroll
  for (int i = 0; i < 8; ++i)
#pragma unroll
    for (int j = 0; j < 4; ++j) acc[i][j] = 0.f;
  for (int k = 0; k < 256; ++k) {
    float4 w = *reinterpret_cast<const float4*>(&W1p[k * 256 + ht * 4]);
    float av[8];
#pragma unroll
    for (int i = 0; i < 8; ++i) av[i] = hs[k * 33 + ai0 + i];
#pragma unroll
    for (int i = 0; i < 8; ++i) {
      acc[i][0] += av[i] * w.x;
      acc[i][1] += av[i] * w.y;
      acc[i][2] += av[i] * w.z;
      acc[i][3] += av[i] * w.w;
    }
  }
  float4 w2 = *reinterpret_cast<const float4*>(&W2[p * 256 + ht * 4]);
#pragma unroll
  for (int i = 0; i < 8; ++i) {
    float v = silu(acc[i][0]) * w2.x + silu(acc[i][1]) * w2.y +
              silu(acc[i][2]) * w2.z + silu(acc[i][3]) * w2.w;
#pragma unroll
    for (int off = 32; off > 0; off >>= 1) v += __shfl_xor(v, off, 64);
    if (ht == 0) {
      int a = a0 + ai0 + i;
      if (a < N_ATOMS) atomicAdd(&out[sid[a]], v);
    }
  }
}

extern "C" void kernel_launch(void* const* d_in, const int* in_sizes, int n_in,
                              void* d_out, int out_size, void* d_ws, size_t ws_size,
                              hipStream_t stream) {
  const float* c0      = (const float*)d_in[0];
  const float* c1      = (const float*)d_in[1];
  const float* c2      = (const float*)d_in[2];
  const float* c3      = (const float*)d_in[3];
  const int*   species = (const int*)d_in[4];
  const int*   sid     = (const int*)d_in[5];
  const float* combW   = (const float*)d_in[6];
  const float* W0      = (const float*)d_in[7];
  const float* W1      = (const float*)d_in[8];
  const float* W2      = (const float*)d_in[9];
  float*       out     = (float*)d_out;

  // ws layout: fh fp16 82.8MB | W0t fp16 8.4MB | h0 fp32 41MB  = ~132MB
  ushort* fh  = (ushort*)d_ws;
  ushort* W0t = fh + (size_t)APAD * NFEAT;
  float*  h0  = (float*)(W0t + (size_t)NP * HID * NFEAT);

  (void)hipMemsetAsync(out, 0, (size_t)out_size * sizeof(float), stream);
  // zero padded tail rows of fh (re-poisoned 0xAA before every launch)
  (void)hipMemsetAsync(fh + (size_t)N_ATOMS * NFEAT, 0,
                       (size_t)(APAD - N_ATOMS) * NFEAT * sizeof(ushort), stream);

  feat_kernel<<<N_ATOMS, 256, 0, stream>>>(c0, c1, c2, c3, fh);

  dim3 gw(HID / 32, NFEAT / 32, NP);
  w0cvt_kernel<<<gw, 256, 0, stream>>>(W0, W0t);

  dim3 g2(1024 / 128, APAD / 128);   // 8 x 79
  gemm0_mfma<<<g2, 256, 0, stream>>>(fh, W0t, combW, species, h0);

  dim3 g3(313, 4);
  mlp_kernel<<<g3, 256, 0, stream>>>(h0, W1, W2, sid, out);
}

// Round 5
// 358.066 us; speedup vs baseline: 4.7990x; 1.3844x over previous
//
#include <hip/hip_runtime.h>
#include <hip/hip_bf16.h>
#include <cstdint>
#include <cstddef>

#define N_ATOMS 10000
#define NSTRUCT 100
#define NP 4
#define NS 4
#define NFEAT 4096
#define HID 256
#define APAD 10112   // 79 tiles of 128

typedef __attribute__((ext_vector_type(8))) _Float16 f16x8;
typedef __attribute__((ext_vector_type(4))) float f32x4;

__device__ __forceinline__ float silu(float x) {
  return x / (1.f + __expf(-x));
}
__device__ __forceinline__ ushort f2h(float x) {
  _Float16 h = (_Float16)x;
  return *reinterpret_cast<ushort*>(&h);
}

typedef __attribute__((address_space(3))) uint32_t lds_u32;
typedef const __attribute__((address_space(1))) uint32_t glb_u32;
__device__ __forceinline__ void glds16(const ushort* g, ushort* l) {
  __builtin_amdgcn_global_load_lds((glb_u32*)g, (lds_u32*)l, 16, 0, 0);
}

// ---------------- Kernel A: power spectrum -> fp16 ----------------
__global__ __launch_bounds__(256) void feat_kernel(
    const float* __restrict__ c0, const float* __restrict__ c1,
    const float* __restrict__ c2, const float* __restrict__ c3,
    ushort* __restrict__ fh) {
  int a = blockIdx.x;
  __shared__ float cs[512];
  int tid = threadIdx.x;
  for (int e = tid; e < 512; e += 256) {
    float v;
    if (e < 32)       v = c0[a * 32  + e];
    else if (e < 128) v = c1[a * 96  + (e - 32)];
    else if (e < 288) v = c2[a * 160 + (e - 128)];
    else              v = c3[a * 224 + (e - 288)];
    cs[e] = v;
  }
  __syncthreads();
  const float cg[4]  = {1.0f, 0.5773502691896258f, 0.4472135954999579f, 0.3779644730092272f};
  const int  off[4]  = {0, 32, 128, 288};
  const int  nm[4]   = {1, 3, 5, 7};
  for (int f = tid; f < NFEAT; f += 256) {
    int l = f >> 10;
    int rem = f & 1023;
    int q = rem >> 5, r = rem & 31;
    const float* base = cs + off[l];
    float s = 0.f;
    for (int m = 0; m < nm[l]; ++m) s += base[m * 32 + q] * base[m * 32 + r];
    fh[(size_t)a * NFEAT + f] = f2h(s * cg[l]);
  }
}

// ---------------- Kernel A2: W0 [p][k][n] fp32 -> W0t [p][n][k] fp16 --------
__global__ __launch_bounds__(256) void w0cvt_kernel(
    const float* __restrict__ W0, ushort* __restrict__ W0t) {
  __shared__ float t[32][33];
  int p = blockIdx.z;
  int kt = blockIdx.y * 32, nt = blockIdx.x * 32;
  int lx = threadIdx.x & 31, ly = threadIdx.x >> 5;
  const float* src = W0 + (size_t)p * NFEAT * HID;
#pragma unroll
  for (int i = 0; i < 4; ++i) {
    int k = kt + ly + i * 8;
    t[ly + i * 8][lx] = src[(size_t)k * HID + nt + lx];
  }
  __syncthreads();
  ushort* dst = W0t + (size_t)p * HID * NFEAT;
#pragma unroll
  for (int i = 0; i < 4; ++i) {
    int n = nt + ly + i * 8;
    dst[(size_t)n * NFEAT + kt + lx] = f2h(t[lx][ly + i * 8]);
  }
}

// ---------------- Kernel A3: W1 [p][k][n] fp32 -> W1t [p][n][k] fp16 --------
__global__ __launch_bounds__(256) void w1cvt_kernel(
    const float* __restrict__ W1, ushort* __restrict__ W1t) {
  __shared__ float t[32][33];
  int p = blockIdx.z;
  int kt = blockIdx.y * 32, nt = blockIdx.x * 32;
  int lx = threadIdx.x & 31, ly = threadIdx.x >> 5;
  const float* src = W1 + (size_t)p * HID * HID;
#pragma unroll
  for (int i = 0; i < 4; ++i) {
    int k = kt + ly + i * 8;
    t[ly + i * 8][lx] = src[(size_t)k * HID + nt + lx];
  }
  __syncthreads();
  ushort* dst = W1t + (size_t)p * HID * HID;
#pragma unroll
  for (int i = 0; i < 4; ++i) {
    int n = nt + ly + i * 8;
    dst[(size_t)n * HID + kt + lx] = f2h(t[lx][ly + i * 8]);
  }
}

// ---------------- Kernel B: fp16 MFMA GEMM0, fused pw*silu, fp16 out --------
// 128x128 tile, BK=32, 4 waves 2x2, each wave 64x64 via 4x4 16x16x32 subtiles.
__global__ __launch_bounds__(256) void gemm0_mfma(
    const ushort* __restrict__ fh, const ushort* __restrict__ W0t,
    const float* __restrict__ combW, const int* __restrict__ species,
    ushort* __restrict__ h0f) {
  __shared__ ushort As[128 * 32];   // [m][k] 64B rows, 8KB
  __shared__ ushort Bs[128 * 32];   // [n][k]
  int tid = threadIdx.x;
  int bm = blockIdx.y * 128;
  int bn = blockIdx.x * 128;
  int wid = tid >> 6, lane = tid & 63;
  int wm = (wid >> 1) * 64, wn = (wid & 1) * 64;

  int srow = tid >> 2, skp = tid & 3;
  const ushort* ga = fh  + ((size_t)(bm + srow) * NFEAT + skp * 8);
  const ushort* gb = W0t + ((size_t)(bn + srow) * NFEAT + skp * 8);
  ushort* lA = As + tid * 8;        // wave-uniform base + lane*16B
  ushort* lB = Bs + tid * 8;
  const size_t half = (size_t)64 * NFEAT;

  f32x4 acc[4][4];
#pragma unroll
  for (int i = 0; i < 4; ++i)
#pragma unroll
    for (int j = 0; j < 4; ++j) acc[i][j] = (f32x4){0.f, 0.f, 0.f, 0.f};

  int mrow = lane & 15;
  int ksel = (lane >> 4) * 8;

  for (int k0 = 0; k0 < NFEAT; k0 += 32) {
    glds16(ga + k0,        lA);
    glds16(ga + k0 + half, lA + 2048);
    glds16(gb + k0,        lB);
    glds16(gb + k0 + half, lB + 2048);
    __syncthreads();

    f16x8 af[4], bf[4];
#pragma unroll
    for (int i = 0; i < 4; ++i) {
      af[i] = *reinterpret_cast<const f16x8*>(&As[(wm + i * 16 + mrow) * 32 + ksel]);
      bf[i] = *reinterpret_cast<const f16x8*>(&Bs[(wn + i * 16 + mrow) * 32 + ksel]);
    }
#pragma unroll
    for (int i = 0; i < 4; ++i)
#pragma unroll
      for (int j = 0; j < 4; ++j)
        acc[i][j] = __builtin_amdgcn_mfma_f32_16x16x32_f16(af[i], bf[j], acc[i][j], 0, 0, 0);
    __syncthreads();
  }

  // epilogue: D row = (lane>>4)*4 + r, col = lane&15; pad rows -> 0
  int p = bn >> 8;
  int col = lane & 15, rbase = (lane >> 4) * 4;
#pragma unroll
  for (int i = 0; i < 4; ++i) {
#pragma unroll
    for (int r = 0; r < 4; ++r) {
      int m = bm + wm + i * 16 + rbase + r;
      bool live = (m < N_ATOMS);
      float pw = live ? combW[p * NS + species[m]] : 0.f;
#pragma unroll
      for (int j = 0; j < 4; ++j) {
        int n = bn + wn + j * 16 + col;
        float v = live ? silu(pw * acc[i][j][r]) : 0.f;
        h0f[(size_t)m * 1024 + n] = f2h(v);
      }
    }
  }
}

// ---------------- Kernel C: layer-1 fp16 MFMA GEMM + silu, fp16 out --------
// A = h0f [a][1024] (per-p 256-col slice), B = W1t [p*256+n][k=256], K=256.
__global__ __launch_bounds__(256) void mlp1_mfma(
    const ushort* __restrict__ h0f, const ushort* __restrict__ W1t,
    ushort* __restrict__ h1f) {
  __shared__ ushort As[128 * 32];
  __shared__ ushort Bs[128 * 32];
  int tid = threadIdx.x;
  int bm = blockIdx.y * 128;
  int bn = blockIdx.x * 128;   // global n in [0,1024)
  int p  = bn >> 8;
  int wid = tid >> 6, lane = tid & 63;
  int wm = (wid >> 1) * 64, wn = (wid & 1) * 64;

  int srow = tid >> 2, skp = tid & 3;
  const ushort* ga = h0f + ((size_t)(bm + srow) * 1024 + p * 256 + skp * 8);
  const ushort* gb = W1t + ((size_t)(bn + srow) * 256 + skp * 8);
  ushort* lA = As + tid * 8;
  ushort* lB = Bs + tid * 8;
  const size_t halfA = (size_t)64 * 1024;
  const size_t halfB = (size_t)64 * 256;

  f32x4 acc[4][4];
#pragma unroll
  for (int i = 0; i < 4; ++i)
#pragma unroll
    for (int j = 0; j < 4; ++j) acc[i][j] = (f32x4){0.f, 0.f, 0.f, 0.f};

  int mrow = lane & 15;
  int ksel = (lane >> 4) * 8;

  for (int k0 = 0; k0 < 256; k0 += 32) {
    glds16(ga + k0,         lA);
    glds16(ga + k0 + halfA, lA + 2048);
    glds16(gb + k0,         lB);
    glds16(gb + k0 + halfB, lB + 2048);
    __syncthreads();

    f16x8 af[4], bf[4];
#pragma unroll
    for (int i = 0; i < 4; ++i) {
      af[i] = *reinterpret_cast<const f16x8*>(&As[(wm + i * 16 + mrow) * 32 + ksel]);
      bf[i] = *reinterpret_cast<const f16x8*>(&Bs[(wn + i * 16 + mrow) * 32 + ksel]);
    }
#pragma unroll
    for (int i = 0; i < 4; ++i)
#pragma unroll
      for (int j = 0; j < 4; ++j)
        acc[i][j] = __builtin_amdgcn_mfma_f32_16x16x32_f16(af[i], bf[j], acc[i][j], 0, 0, 0);
    __syncthreads();
  }

  int col = lane & 15, rbase = (lane >> 4) * 4;
#pragma unroll
  for (int i = 0; i < 4; ++i) {
#pragma unroll
    for (int r = 0; r < 4; ++r) {
      int m = bm + wm + i * 16 + rbase + r;
      if (m >= N_ATOMS) continue;
#pragma unroll
      for (int j = 0; j < 4; ++j) {
        int n = bn + wn + j * 16 + col;
        h1f[(size_t)m * 1024 + n] = f2h(silu(acc[i][j][r]));
      }
    }
  }
}

// ---------------- Kernel D: layer-2 dot + segment-sum ----------------
// One wave per atom: v = sum_j h1[a,j]*W2flat[j]; atomicAdd(out[sid[a]]).
__global__ __launch_bounds__(256) void final_kernel(
    const ushort* __restrict__ h1f, const float* __restrict__ W2,
    const int* __restrict__ sid, float* __restrict__ out) {
  int wv = threadIdx.x >> 6, lane = threadIdx.x & 63;
  int a = blockIdx.x * 4 + wv;
  if (a >= N_ATOMS) return;
  const ushort* hrow = h1f + (size_t)a * 1024 + lane * 16;
  f16x8 h1 = *reinterpret_cast<const f16x8*>(hrow);
  f16x8 h2 = *reinterpret_cast<const f16x8*>(hrow + 8);
  const float* w2 = W2 + lane * 16;
  float v = 0.f;
#pragma unroll
  for (int t = 0; t < 8; ++t) v += (float)h1[t] * w2[t];
#pragma unroll
  for (int t = 0; t < 8; ++t) v += (float)h2[t] * w2[8 + t];
#pragma unroll
  for (int off = 32; off > 0; off >>= 1) v += __shfl_xor(v, off, 64);
  if (lane == 0) atomicAdd(&out[sid[a]], v);
}

extern "C" void kernel_launch(void* const* d_in, const int* in_sizes, int n_in,
                              void* d_out, int out_size, void* d_ws, size_t ws_size,
                              hipStream_t stream) {
  const float* c0      = (const float*)d_in[0];
  const float* c1      = (const float*)d_in[1];
  const float* c2      = (const float*)d_in[2];
  const float* c3      = (const float*)d_in[3];
  const int*   species = (const int*)d_in[4];
  const int*   sid     = (const int*)d_in[5];
  const float* combW   = (const float*)d_in[6];
  const float* W0      = (const float*)d_in[7];
  const float* W1      = (const float*)d_in[8];
  const float* W2      = (const float*)d_in[9];
  float*       out     = (float*)d_out;

  // ws: fh 82.8MB | W0t 8.4MB | W1t 0.5MB | h0f 20.7MB | h1f 20.5MB = ~133MB
  ushort* fh  = (ushort*)d_ws;
  ushort* W0t = fh  + (size_t)APAD * NFEAT;
  ushort* W1t = W0t + (size_t)NP * HID * NFEAT;
  ushort* h0f = W1t + (size_t)NP * HID * HID;
  ushort* h1f = h0f + (size_t)APAD * 1024;

  (void)hipMemsetAsync(out, 0, (size_t)out_size * sizeof(float), stream);
  (void)hipMemsetAsync(fh + (size_t)N_ATOMS * NFEAT, 0,
                       (size_t)(APAD - N_ATOMS) * NFEAT * sizeof(ushort), stream);

  feat_kernel<<<N_ATOMS, 256, 0, stream>>>(c0, c1, c2, c3, fh);

  dim3 gw(HID / 32, NFEAT / 32, NP);
  w0cvt_kernel<<<gw, 256, 0, stream>>>(W0, W0t);
  dim3 gw1(HID / 32, HID / 32, NP);
  w1cvt_kernel<<<gw1, 256, 0, stream>>>(W1, W1t);

  dim3 g2(1024 / 128, APAD / 128);   // 8 x 79
  gemm0_mfma<<<g2, 256, 0, stream>>>(fh, W0t, combW, species, h0f);

  dim3 g3(1024 / 128, APAD / 128);   // 8 x 79
  mlp1_mfma<<<g3, 256, 0, stream>>>(h0f, W1t, h1f);

  final_kernel<<<2500, 256, 0, stream>>>(h1f, W2, sid, out);
}

// Round 6
// 340.958 us; speedup vs baseline: 5.0398x; 1.0502x over previous
//
#include <hip/hip_runtime.h>
#include <hip/hip_bf16.h>
#include <cstdint>
#include <cstddef>

#define N_ATOMS 10000
#define NSTRUCT 100
#define NP 4
#define NS 4
#define NFEAT 4096
#define HID 256
#define APAD 10112   // 79 tiles of 128

typedef __attribute__((ext_vector_type(8))) _Float16 f16x8;
typedef __attribute__((ext_vector_type(8))) ushort u16x8;
typedef __attribute__((ext_vector_type(4))) float f32x4;

__device__ __forceinline__ float silu(float x) {
  return x / (1.f + __expf(-x));
}
__device__ __forceinline__ ushort f2h(float x) {
  _Float16 h = (_Float16)x;
  return *reinterpret_cast<ushort*>(&h);
}

typedef __attribute__((address_space(3))) uint32_t lds_u32;
typedef const __attribute__((address_space(1))) uint32_t glb_u32;
__device__ __forceinline__ void glds16(const ushort* g, ushort* l) {
  __builtin_amdgcn_global_load_lds((glb_u32*)g, (lds_u32*)l, 16, 0, 0);
}

// ---------------- Kernel A: power spectrum -> fp16, 8-wide chunks ----------
// feat[a, l*1024 + q*32 + r]; thread computes 8 consecutive r per chunk.
__global__ __launch_bounds__(256) void feat_kernel(
    const float* __restrict__ c0, const float* __restrict__ c1,
    const float* __restrict__ c2, const float* __restrict__ c3,
    ushort* __restrict__ fh) {
  int a = blockIdx.x;
  __shared__ float cs[512];
  int tid = threadIdx.x;
  for (int e = tid; e < 512; e += 256) {
    float v;
    if (e < 32)       v = c0[a * 32  + e];
    else if (e < 128) v = c1[a * 96  + (e - 32)];
    else if (e < 288) v = c2[a * 160 + (e - 128)];
    else              v = c3[a * 224 + (e - 288)];
    cs[e] = v;
  }
  __syncthreads();
  const float cg[4]  = {1.0f, 0.5773502691896258f, 0.4472135954999579f, 0.3779644730092272f};
  const int  off[4]  = {0, 32, 128, 288};
  const int  nm[4]   = {1, 3, 5, 7};
#pragma unroll
  for (int it = 0; it < 2; ++it) {
    int cc = tid + it * 256;          // chunk id in [0,512)
    int l = cc >> 7;
    int rem = cc & 127;
    int q = rem >> 2, rc = (rem & 3) * 8;
    const float* base = cs + off[l];
    float s[8] = {0.f, 0.f, 0.f, 0.f, 0.f, 0.f, 0.f, 0.f};
    for (int m = 0; m < nm[l]; ++m) {
      float bq = base[m * 32 + q];                       // wave-broadcast
      float4 v0 = *reinterpret_cast<const float4*>(&base[m * 32 + rc]);
      float4 v1 = *reinterpret_cast<const float4*>(&base[m * 32 + rc + 4]);
      s[0] += bq * v0.x; s[1] += bq * v0.y; s[2] += bq * v0.z; s[3] += bq * v0.w;
      s[4] += bq * v1.x; s[5] += bq * v1.y; s[6] += bq * v1.z; s[7] += bq * v1.w;
    }
    u16x8 o;
#pragma unroll
    for (int t = 0; t < 8; ++t) o[t] = f2h(s[t] * cg[l]);
    *reinterpret_cast<u16x8*>(&fh[(size_t)a * NFEAT + cc * 8]) = o;
  }
}

// ---------------- Kernel A2: W0 [p][k][n] fp32 -> W0t [p][n][k] fp16 --------
__global__ __launch_bounds__(256) void w0cvt_kernel(
    const float* __restrict__ W0, ushort* __restrict__ W0t) {
  __shared__ float t[32][33];
  int p = blockIdx.z;
  int kt = blockIdx.y * 32, nt = blockIdx.x * 32;
  int lx = threadIdx.x & 31, ly = threadIdx.x >> 5;
  const float* src = W0 + (size_t)p * NFEAT * HID;
#pragma unroll
  for (int i = 0; i < 4; ++i) {
    int k = kt + ly + i * 8;
    t[ly + i * 8][lx] = src[(size_t)k * HID + nt + lx];
  }
  __syncthreads();
  ushort* dst = W0t + (size_t)p * HID * NFEAT;
#pragma unroll
  for (int i = 0; i < 4; ++i) {
    int n = nt + ly + i * 8;
    dst[(size_t)n * NFEAT + kt + lx] = f2h(t[lx][ly + i * 8]);
  }
}

// ---------------- Kernel A3: W1 [p][k][n] fp32 -> W1t [p][n][k] fp16 --------
__global__ __launch_bounds__(256) void w1cvt_kernel(
    const float* __restrict__ W1, ushort* __restrict__ W1t) {
  __shared__ float t[32][33];
  int p = blockIdx.z;
  int kt = blockIdx.y * 32, nt = blockIdx.x * 32;
  int lx = threadIdx.x & 31, ly = threadIdx.x >> 5;
  const float* src = W1 + (size_t)p * HID * HID;
#pragma unroll
  for (int i = 0; i < 4; ++i) {
    int k = kt + ly + i * 8;
    t[ly + i * 8][lx] = src[(size_t)k * HID + nt + lx];
  }
  __syncthreads();
  ushort* dst = W1t + (size_t)p * HID * HID;
#pragma unroll
  for (int i = 0; i < 4; ++i) {
    int n = nt + ly + i * 8;
    dst[(size_t)n * HID + kt + lx] = f2h(t[lx][ly + i * 8]);
  }
}

// ---------------- Kernel B: fp16 MFMA GEMM0, BK=64, XOR-swizzled LDS -------
// 128x128 tile, BK=64, 4 waves 2x2. LDS row = 64 k (128B); logical k-chunk c
// of row r stored at column (c ^ (r&7)) -> conflict-free b128 reads.
__global__ __launch_bounds__(256) void gemm0_mfma(
    const ushort* __restrict__ fh, const ushort* __restrict__ W0t,
    const float* __restrict__ combW, const int* __restrict__ species,
    ushort* __restrict__ h0f) {
  __shared__ ushort As[128 * 64];   // 16KB
  __shared__ ushort Bs[128 * 64];   // 16KB
  int tid = threadIdx.x;
  int bm = blockIdx.y * 128;
  int bn = blockIdx.x * 128;
  int wid = tid >> 6, lane = tid & 63;
  int wm = (wid >> 1) * 64, wn = (wid & 1) * 64;

  // staging: ids id = tid + t*256, t<4: row = (tid>>3)+t*32, kp = tid&7
  int row0 = tid >> 3;
  int kidx = (tid & 7) ^ (row0 & 7);       // constant across t (32&7==0)
  const ushort* gaA = fh  + ((size_t)(bm + row0) * NFEAT + kidx * 8);
  const ushort* gaB = W0t + ((size_t)(bn + row0) * NFEAT + kidx * 8);
  ushort* lA = As + tid * 8;
  ushort* lB = Bs + tid * 8;
  const size_t rstep = (size_t)32 * NFEAT;

  f32x4 acc[4][4];
#pragma unroll
  for (int i = 0; i < 4; ++i)
#pragma unroll
    for (int j = 0; j < 4; ++j) acc[i][j] = (f32x4){0.f, 0.f, 0.f, 0.f};

  int mrow = lane & 15;
  int h7 = mrow & 7;
  int qv = lane >> 4;                      // logical chunk base (0..3)

  for (int k0 = 0; k0 < NFEAT; k0 += 64) {
#pragma unroll
    for (int t = 0; t < 4; ++t) {
      glds16(gaA + k0 + t * rstep, lA + t * 2048);
      glds16(gaB + k0 + t * rstep, lB + t * 2048);
    }
    __syncthreads();

#pragma unroll
    for (int kk = 0; kk < 2; ++kk) {
      int c = qv + kk * 4;
      int sw = (c ^ h7) * 8;
      f16x8 af[4], bf[4];
#pragma unroll
      for (int i = 0; i < 4; ++i) {
        af[i] = *reinterpret_cast<const f16x8*>(&As[(wm + i * 16 + mrow) * 64 + sw]);
        bf[i] = *reinterpret_cast<const f16x8*>(&Bs[(wn + i * 16 + mrow) * 64 + sw]);
      }
#pragma unroll
      for (int i = 0; i < 4; ++i)
#pragma unroll
        for (int j = 0; j < 4; ++j)
          acc[i][j] = __builtin_amdgcn_mfma_f32_16x16x32_f16(af[i], bf[j], acc[i][j], 0, 0, 0);
    }
    __syncthreads();
  }

  // epilogue: D row = (lane>>4)*4 + r, col = lane&15; pad rows -> 0
  int p = bn >> 8;
  int col = lane & 15, rbase = (lane >> 4) * 4;
#pragma unroll
  for (int i = 0; i < 4; ++i) {
#pragma unroll
    for (int r = 0; r < 4; ++r) {
      int m = bm + wm + i * 16 + rbase + r;
      bool live = (m < N_ATOMS);
      float pw = live ? combW[p * NS + species[m]] : 0.f;
#pragma unroll
      for (int j = 0; j < 4; ++j) {
        int n = bn + wn + j * 16 + col;
        float v = live ? silu(pw * acc[i][j][r]) : 0.f;
        h0f[(size_t)m * 1024 + n] = f2h(v);
      }
    }
  }
}

// ---------------- Kernel C: layer-1 fp16 MFMA GEMM + silu, fp16 out --------
// A = h0f [a][1024] (per-p 256-col slice), B = W1t [p*256+n][k=256], K=256.
__global__ __launch_bounds__(256) void mlp1_mfma(
    const ushort* __restrict__ h0f, const ushort* __restrict__ W1t,
    ushort* __restrict__ h1f) {
  __shared__ ushort As[128 * 32];
  __shared__ ushort Bs[128 * 32];
  int tid = threadIdx.x;
  int bm = blockIdx.y * 128;
  int bn = blockIdx.x * 128;   // global n in [0,1024)
  int p  = bn >> 8;
  int wid = tid >> 6, lane = tid & 63;
  int wm = (wid >> 1) * 64, wn = (wid & 1) * 64;

  int srow = tid >> 2, skp = tid & 3;
  const ushort* ga = h0f + ((size_t)(bm + srow) * 1024 + p * 256 + skp * 8);
  const ushort* gb = W1t + ((size_t)(bn + srow) * 256 + skp * 8);
  ushort* lA = As + tid * 8;
  ushort* lB = Bs + tid * 8;
  const size_t halfA = (size_t)64 * 1024;
  const size_t halfB = (size_t)64 * 256;

  f32x4 acc[4][4];
#pragma unroll
  for (int i = 0; i < 4; ++i)
#pragma unroll
    for (int j = 0; j < 4; ++j) acc[i][j] = (f32x4){0.f, 0.f, 0.f, 0.f};

  int mrow = lane & 15;
  int ksel = (lane >> 4) * 8;

  for (int k0 = 0; k0 < 256; k0 += 32) {
    glds16(ga + k0,         lA);
    glds16(ga + k0 + halfA, lA + 2048);
    glds16(gb + k0,         lB);
    glds16(gb + k0 + halfB, lB + 2048);
    __syncthreads();

    f16x8 af[4], bf[4];
#pragma unroll
    for (int i = 0; i < 4; ++i) {
      af[i] = *reinterpret_cast<const f16x8*>(&As[(wm + i * 16 + mrow) * 32 + ksel]);
      bf[i] = *reinterpret_cast<const f16x8*>(&Bs[(wn + i * 16 + mrow) * 32 + ksel]);
    }
#pragma unroll
    for (int i = 0; i < 4; ++i)
#pragma unroll
      for (int j = 0; j < 4; ++j)
        acc[i][j] = __builtin_amdgcn_mfma_f32_16x16x32_f16(af[i], bf[j], acc[i][j], 0, 0, 0);
    __syncthreads();
  }

  int col = lane & 15, rbase = (lane >> 4) * 4;
#pragma unroll
  for (int i = 0; i < 4; ++i) {
#pragma unroll
    for (int r = 0; r < 4; ++r) {
      int m = bm + wm + i * 16 + rbase + r;
      if (m >= N_ATOMS) continue;
#pragma unroll
      for (int j = 0; j < 4; ++j) {
        int n = bn + wn + j * 16 + col;
        h1f[(size_t)m * 1024 + n] = f2h(silu(acc[i][j][r]));
      }
    }
  }
}

// ---------------- Kernel D: layer-2 dot + segment-sum ----------------
__global__ __launch_bounds__(256) void final_kernel(
    const ushort* __restrict__ h1f, const float* __restrict__ W2,
    const int* __restrict__ sid, float* __restrict__ out) {
  int wv = threadIdx.x >> 6, lane = threadIdx.x & 63;
  int a = blockIdx.x * 4 + wv;
  if (a >= N_ATOMS) return;
  const ushort* hrow = h1f + (size_t)a * 1024 + lane * 16;
  f16x8 h1 = *reinterpret_cast<const f16x8*>(hrow);
  f16x8 h2 = *reinterpret_cast<const f16x8*>(hrow + 8);
  const float* w2 = W2 + lane * 16;
  float v = 0.f;
#pragma unroll
  for (int t = 0; t < 8; ++t) v += (float)h1[t] * w2[t];
#pragma unroll
  for (int t = 0; t < 8; ++t) v += (float)h2[t] * w2[8 + t];
#pragma unroll
  for (int off = 32; off > 0; off >>= 1) v += __shfl_xor(v, off, 64);
  if (lane == 0) atomicAdd(&out[sid[a]], v);
}

extern "C" void kernel_launch(void* const* d_in, const int* in_sizes, int n_in,
                              void* d_out, int out_size, void* d_ws, size_t ws_size,
                              hipStream_t stream) {
  const float* c0      = (const float*)d_in[0];
  const float* c1      = (const float*)d_in[1];
  const float* c2      = (const float*)d_in[2];
  const float* c3      = (const float*)d_in[3];
  const int*   species = (const int*)d_in[4];
  const int*   sid     = (const int*)d_in[5];
  const float* combW   = (const float*)d_in[6];
  const float* W0      = (const float*)d_in[7];
  const float* W1      = (const float*)d_in[8];
  const float* W2      = (const float*)d_in[9];
  float*       out     = (float*)d_out;

  // ws: fh 82.8MB | W0t 8.4MB | W1t 0.5MB | h0f 20.7MB | h1f 20.5MB = ~133MB
  ushort* fh  = (ushort*)d_ws;
  ushort* W0t = fh  + (size_t)APAD * NFEAT;
  ushort* W1t = W0t + (size_t)NP * HID * NFEAT;
  ushort* h0f = W1t + (size_t)NP * HID * HID;
  ushort* h1f = h0f + (size_t)APAD * 1024;

  (void)hipMemsetAsync(out, 0, (size_t)out_size * sizeof(float), stream);
  (void)hipMemsetAsync(fh + (size_t)N_ATOMS * NFEAT, 0,
                       (size_t)(APAD - N_ATOMS) * NFEAT * sizeof(ushort), stream);

  feat_kernel<<<N_ATOMS, 256, 0, stream>>>(c0, c1, c2, c3, fh);

  dim3 gw(HID / 32, NFEAT / 32, NP);
  w0cvt_kernel<<<gw, 256, 0, stream>>>(W0, W0t);
  dim3 gw1(HID / 32, HID / 32, NP);
  w1cvt_kernel<<<gw1, 256, 0, stream>>>(W1, W1t);

  dim3 g2(1024 / 128, APAD / 128);   // 8 x 79
  gemm0_mfma<<<g2, 256, 0, stream>>>(fh, W0t, combW, species, h0f);

  dim3 g3(1024 / 128, APAD / 128);   // 8 x 79
  mlp1_mfma<<<g3, 256, 0, stream>>>(h0f, W1t, h1f);

  final_kernel<<<2500, 256, 0, stream>>>(h1f, W2, sid, out);
}

// Round 7
// 317.378 us; speedup vs baseline: 5.4143x; 1.0743x over previous
//
#include <hip/hip_runtime.h>
#include <hip/hip_bf16.h>
#include <cstdint>
#include <cstddef>

#define N_ATOMS 10000
#define NSTRUCT 100
#define NP 4
#define NS 4
#define NFEAT 4096
#define HID 256
#define APAD 10112   // 79 tiles of 128

typedef __attribute__((ext_vector_type(8))) _Float16 f16x8;
typedef __attribute__((ext_vector_type(8))) ushort u16x8;
typedef __attribute__((ext_vector_type(4))) float f32x4;

__device__ __forceinline__ float silu(float x) {
  return x / (1.f + __expf(-x));
}
__device__ __forceinline__ ushort f2h(float x) {
  _Float16 h = (_Float16)x;
  return *reinterpret_cast<ushort*>(&h);
}

typedef __attribute__((address_space(3))) uint32_t lds_u32;
typedef const __attribute__((address_space(1))) uint32_t glb_u32;
__device__ __forceinline__ void glds16(const ushort* g, ushort* l) {
  __builtin_amdgcn_global_load_lds((glb_u32*)g, (lds_u32*)l, 16, 0, 0);
}

// ---------------- Kernel A: power spectrum -> fp16, 8-wide chunks ----------
__global__ __launch_bounds__(256) void feat_kernel(
    const float* __restrict__ c0, const float* __restrict__ c1,
    const float* __restrict__ c2, const float* __restrict__ c3,
    ushort* __restrict__ fh) {
  int a = blockIdx.x;
  __shared__ float cs[512];
  int tid = threadIdx.x;
  for (int e = tid; e < 512; e += 256) {
    float v;
    if (e < 32)       v = c0[a * 32  + e];
    else if (e < 128) v = c1[a * 96  + (e - 32)];
    else if (e < 288) v = c2[a * 160 + (e - 128)];
    else              v = c3[a * 224 + (e - 288)];
    cs[e] = v;
  }
  __syncthreads();
  const float cg[4]  = {1.0f, 0.5773502691896258f, 0.4472135954999579f, 0.3779644730092272f};
  const int  off[4]  = {0, 32, 128, 288};
  const int  nm[4]   = {1, 3, 5, 7};
#pragma unroll
  for (int it = 0; it < 2; ++it) {
    int cc = tid + it * 256;          // chunk id in [0,512)
    int l = cc >> 7;
    int rem = cc & 127;
    int q = rem >> 2, rc = (rem & 3) * 8;
    const float* base = cs + off[l];
    float s[8] = {0.f, 0.f, 0.f, 0.f, 0.f, 0.f, 0.f, 0.f};
    for (int m = 0; m < nm[l]; ++m) {
      float bq = base[m * 32 + q];                       // wave-broadcast
      float4 v0 = *reinterpret_cast<const float4*>(&base[m * 32 + rc]);
      float4 v1 = *reinterpret_cast<const float4*>(&base[m * 32 + rc + 4]);
      s[0] += bq * v0.x; s[1] += bq * v0.y; s[2] += bq * v0.z; s[3] += bq * v0.w;
      s[4] += bq * v1.x; s[5] += bq * v1.y; s[6] += bq * v1.z; s[7] += bq * v1.w;
    }
    u16x8 o;
#pragma unroll
    for (int t = 0; t < 8; ++t) o[t] = f2h(s[t] * cg[l]);
    *reinterpret_cast<u16x8*>(&fh[(size_t)a * NFEAT + cc * 8]) = o;
  }
}

// ---------------- Kernel A2: W0 [p][k][n] fp32 -> W0t [p][n][k] fp16 --------
__global__ __launch_bounds__(256) void w0cvt_kernel(
    const float* __restrict__ W0, ushort* __restrict__ W0t) {
  __shared__ float t[32][33];
  int p = blockIdx.z;
  int kt = blockIdx.y * 32, nt = blockIdx.x * 32;
  int lx = threadIdx.x & 31, ly = threadIdx.x >> 5;
  const float* src = W0 + (size_t)p * NFEAT * HID;
#pragma unroll
  for (int i = 0; i < 4; ++i) {
    int k = kt + ly + i * 8;
    t[ly + i * 8][lx] = src[(size_t)k * HID + nt + lx];
  }
  __syncthreads();
  ushort* dst = W0t + (size_t)p * HID * NFEAT;
#pragma unroll
  for (int i = 0; i < 4; ++i) {
    int n = nt + ly + i * 8;
    dst[(size_t)n * NFEAT + kt + lx] = f2h(t[lx][ly + i * 8]);
  }
}

// ---------------- Kernel A3: W1 [p][k][n] fp32 -> W1t [p][n][k] fp16 --------
__global__ __launch_bounds__(256) void w1cvt_kernel(
    const float* __restrict__ W1, ushort* __restrict__ W1t) {
  __shared__ float t[32][33];
  int p = blockIdx.z;
  int kt = blockIdx.y * 32, nt = blockIdx.x * 32;
  int lx = threadIdx.x & 31, ly = threadIdx.x >> 5;
  const float* src = W1 + (size_t)p * HID * HID;
#pragma unroll
  for (int i = 0; i < 4; ++i) {
    int k = kt + ly + i * 8;
    t[ly + i * 8][lx] = src[(size_t)k * HID + nt + lx];
  }
  __syncthreads();
  ushort* dst = W1t + (size_t)p * HID * HID;
#pragma unroll
  for (int i = 0; i < 4; ++i) {
    int n = nt + ly + i * 8;
    dst[(size_t)n * HID + kt + lx] = f2h(t[lx][ly + i * 8]);
  }
}

// ---------------- Kernel B: fp16 MFMA GEMM0, BK=32, XOR-swizzled LDS -------
// 128x128 tile, BK=32, 4 waves 2x2. LDS row = 32 k (64B); logical 16B chunk c
// of row r stored at chunk (c ^ (r&3)) -> each 16-lane phase spans 32 banks.
__global__ __launch_bounds__(256) void gemm0_mfma(
    const ushort* __restrict__ fh, const ushort* __restrict__ W0t,
    const float* __restrict__ combW, const int* __restrict__ species,
    ushort* __restrict__ h0f) {
  __shared__ ushort As[128 * 32];   // 8KB
  __shared__ ushort Bs[128 * 32];   // 8KB
  int tid = threadIdx.x;
  int bm = blockIdx.y * 128;
  int bn = blockIdx.x * 128;
  int wid = tid >> 6, lane = tid & 63;
  int wm = (wid >> 1) * 64, wn = (wid & 1) * 64;

  // staging: row = tid>>2 (+64 for 2nd half), chunk = (tid&3)^(row&3)
  int row0 = tid >> 2;
  int kidx = (tid & 3) ^ (row0 & 3);       // 64&3==0 so constant across halves
  const ushort* gaA = fh  + ((size_t)(bm + row0) * NFEAT + kidx * 8);
  const ushort* gaB = W0t + ((size_t)(bn + row0) * NFEAT + kidx * 8);
  ushort* lA = As + tid * 8;
  ushort* lB = Bs + tid * 8;
  const size_t half = (size_t)64 * NFEAT;

  f32x4 acc[4][4];
#pragma unroll
  for (int i = 0; i < 4; ++i)
#pragma unroll
    for (int j = 0; j < 4; ++j) acc[i][j] = (f32x4){0.f, 0.f, 0.f, 0.f};

  int mrow = lane & 15;
  int key = mrow & 3;
  int qv = lane >> 4;                      // logical chunk (0..3)

  for (int k0 = 0; k0 < NFEAT; k0 += 32) {
    glds16(gaA + k0,        lA);
    glds16(gaA + k0 + half, lA + 2048);
    glds16(gaB + k0,        lB);
    glds16(gaB + k0 + half, lB + 2048);
    __syncthreads();

    int sw = (qv ^ key) * 8;
    f16x8 af[4], bf[4];
#pragma unroll
    for (int i = 0; i < 4; ++i) {
      af[i] = *reinterpret_cast<const f16x8*>(&As[(wm + i * 16 + mrow) * 32 + sw]);
      bf[i] = *reinterpret_cast<const f16x8*>(&Bs[(wn + i * 16 + mrow) * 32 + sw]);
    }
#pragma unroll
    for (int i = 0; i < 4; ++i)
#pragma unroll
      for (int j = 0; j < 4; ++j)
        acc[i][j] = __builtin_amdgcn_mfma_f32_16x16x32_f16(af[i], bf[j], acc[i][j], 0, 0, 0);
    __syncthreads();
  }

  // epilogue: D row = (lane>>4)*4 + r, col = lane&15; pad rows -> 0
  int p = bn >> 8;
  int col = lane & 15, rbase = (lane >> 4) * 4;
#pragma unroll
  for (int i = 0; i < 4; ++i) {
#pragma unroll
    for (int r = 0; r < 4; ++r) {
      int m = bm + wm + i * 16 + rbase + r;
      bool live = (m < N_ATOMS);
      float pw = live ? combW[p * NS + species[m]] : 0.f;
#pragma unroll
      for (int j = 0; j < 4; ++j) {
        int n = bn + wn + j * 16 + col;
        float v = live ? silu(pw * acc[i][j][r]) : 0.f;
        h0f[(size_t)m * 1024 + n] = f2h(v);
      }
    }
  }
}

// ---------------- Kernel C: layer-1 fp16 MFMA GEMM + silu, swizzled --------
__global__ __launch_bounds__(256) void mlp1_mfma(
    const ushort* __restrict__ h0f, const ushort* __restrict__ W1t,
    ushort* __restrict__ h1f) {
  __shared__ ushort As[128 * 32];
  __shared__ ushort Bs[128 * 32];
  int tid = threadIdx.x;
  int bm = blockIdx.y * 128;
  int bn = blockIdx.x * 128;   // global n in [0,1024)
  int p  = bn >> 8;
  int wid = tid >> 6, lane = tid & 63;
  int wm = (wid >> 1) * 64, wn = (wid & 1) * 64;

  int row0 = tid >> 2;
  int kidx = (tid & 3) ^ (row0 & 3);
  const ushort* ga = h0f + ((size_t)(bm + row0) * 1024 + p * 256 + kidx * 8);
  const ushort* gb = W1t + ((size_t)(bn + row0) * 256 + kidx * 8);
  ushort* lA = As + tid * 8;
  ushort* lB = Bs + tid * 8;
  const size_t halfA = (size_t)64 * 1024;
  const size_t halfB = (size_t)64 * 256;

  f32x4 acc[4][4];
#pragma unroll
  for (int i = 0; i < 4; ++i)
#pragma unroll
    for (int j = 0; j < 4; ++j) acc[i][j] = (f32x4){0.f, 0.f, 0.f, 0.f};

  int mrow = lane & 15;
  int key = mrow & 3;
  int qv = lane >> 4;

  for (int k0 = 0; k0 < 256; k0 += 32) {
    glds16(ga + k0,         lA);
    glds16(ga + k0 + halfA, lA + 2048);
    glds16(gb + k0,         lB);
    glds16(gb + k0 + halfB, lB + 2048);
    __syncthreads();

    int sw = (qv ^ key) * 8;
    f16x8 af[4], bf[4];
#pragma unroll
    for (int i = 0; i < 4; ++i) {
      af[i] = *reinterpret_cast<const f16x8*>(&As[(wm + i * 16 + mrow) * 32 + sw]);
      bf[i] = *reinterpret_cast<const f16x8*>(&Bs[(wn + i * 16 + mrow) * 32 + sw]);
    }
#pragma unroll
    for (int i = 0; i < 4; ++i)
#pragma unroll
      for (int j = 0; j < 4; ++j)
        acc[i][j] = __builtin_amdgcn_mfma_f32_16x16x32_f16(af[i], bf[j], acc[i][j], 0, 0, 0);
    __syncthreads();
  }

  int col = lane & 15, rbase = (lane >> 4) * 4;
#pragma unroll
  for (int i = 0; i < 4; ++i) {
#pragma unroll
    for (int r = 0; r < 4; ++r) {
      int m = bm + wm + i * 16 + rbase + r;
      if (m >= N_ATOMS) continue;
#pragma unroll
      for (int j = 0; j < 4; ++j) {
        int n = bn + wn + j * 16 + col;
        h1f[(size_t)m * 1024 + n] = f2h(silu(acc[i][j][r]));
      }
    }
  }
}

// ---------------- Kernel D: layer-2 dot + segment-sum ----------------
__global__ __launch_bounds__(256) void final_kernel(
    const ushort* __restrict__ h1f, const float* __restrict__ W2,
    const int* __restrict__ sid, float* __restrict__ out) {
  int wv = threadIdx.x >> 6, lane = threadIdx.x & 63;
  int a = blockIdx.x * 4 + wv;
  if (a >= N_ATOMS) return;
  const ushort* hrow = h1f + (size_t)a * 1024 + lane * 16;
  f16x8 h1 = *reinterpret_cast<const f16x8*>(hrow);
  f16x8 h2 = *reinterpret_cast<const f16x8*>(hrow + 8);
  const float* w2 = W2 + lane * 16;
  float v = 0.f;
#pragma unroll
  for (int t = 0; t < 8; ++t) v += (float)h1[t] * w2[t];
#pragma unroll
  for (int t = 0; t < 8; ++t) v += (float)h2[t] * w2[8 + t];
#pragma unroll
  for (int off = 32; off > 0; off >>= 1) v += __shfl_xor(v, off, 64);
  if (lane == 0) atomicAdd(&out[sid[a]], v);
}

extern "C" void kernel_launch(void* const* d_in, const int* in_sizes, int n_in,
                              void* d_out, int out_size, void* d_ws, size_t ws_size,
                              hipStream_t stream) {
  const float* c0      = (const float*)d_in[0];
  const float* c1      = (const float*)d_in[1];
  const float* c2      = (const float*)d_in[2];
  const float* c3      = (const float*)d_in[3];
  const int*   species = (const int*)d_in[4];
  const int*   sid     = (const int*)d_in[5];
  const float* combW   = (const float*)d_in[6];
  const float* W0      = (const float*)d_in[7];
  const float* W1      = (const float*)d_in[8];
  const float* W2      = (const float*)d_in[9];
  float*       out     = (float*)d_out;

  // ws: fh 82.8MB | W0t 8.4MB | W1t 0.5MB | h0f 20.7MB | h1f 20.5MB = ~133MB
  ushort* fh  = (ushort*)d_ws;
  ushort* W0t = fh  + (size_t)APAD * NFEAT;
  ushort* W1t = W0t + (size_t)NP * HID * NFEAT;
  ushort* h0f = W1t + (size_t)NP * HID * HID;
  ushort* h1f = h0f + (size_t)APAD * 1024;

  (void)hipMemsetAsync(out, 0, (size_t)out_size * sizeof(float), stream);
  (void)hipMemsetAsync(fh + (size_t)N_ATOMS * NFEAT, 0,
                       (size_t)(APAD - N_ATOMS) * NFEAT * sizeof(ushort), stream);

  feat_kernel<<<N_ATOMS, 256, 0, stream>>>(c0, c1, c2, c3, fh);

  dim3 gw(HID / 32, NFEAT / 32, NP);
  w0cvt_kernel<<<gw, 256, 0, stream>>>(W0, W0t);
  dim3 gw1(HID / 32, HID / 32, NP);
  w1cvt_kernel<<<gw1, 256, 0, stream>>>(W1, W1t);

  dim3 g2(1024 / 128, APAD / 128);   // 8 x 79
  gemm0_mfma<<<g2, 256, 0, stream>>>(fh, W0t, combW, species, h0f);

  dim3 g3(1024 / 128, APAD / 128);   // 8 x 79
  mlp1_mfma<<<g3, 256, 0, stream>>>(h0f, W1t, h1f);

  final_kernel<<<2500, 256, 0, stream>>>(h1f, W2, sid, out);
}

// Round 8
// 298.089 us; speedup vs baseline: 5.7646x; 1.0647x over previous
//
#include <hip/hip_runtime.h>
#include <hip/hip_bf16.h>
#include <cstdint>
#include <cstddef>

#define N_ATOMS 10000
#define NSTRUCT 100
#define NP 4
#define NS 4
#define NFEAT 4096
#define HID 256
#define APAD 10240   // 80 tiles of 128 (XCD remap needs a multiple of 8 tiles)

typedef __attribute__((ext_vector_type(8))) _Float16 f16x8;
typedef __attribute__((ext_vector_type(8))) ushort u16x8;
typedef __attribute__((ext_vector_type(4))) float f32x4;

__device__ __forceinline__ float silu(float x) {
  return x / (1.f + __expf(-x));
}
__device__ __forceinline__ ushort f2h(float x) {
  _Float16 h = (_Float16)x;
  return *reinterpret_cast<ushort*>(&h);
}

typedef __attribute__((address_space(3))) uint32_t lds_u32;
typedef const __attribute__((address_space(1))) uint32_t glb_u32;
__device__ __forceinline__ void glds16(const ushort* g, ushort* l) {
  __builtin_amdgcn_global_load_lds((glb_u32*)g, (lds_u32*)l, 16, 0, 0);
}

// ---------------- Kernel A: power spectrum -> fp16, 8-wide chunks ----------
__global__ __launch_bounds__(256) void feat_kernel(
    const float* __restrict__ c0, const float* __restrict__ c1,
    const float* __restrict__ c2, const float* __restrict__ c3,
    ushort* __restrict__ fh) {
  int a = blockIdx.x;
  __shared__ float cs[512];
  int tid = threadIdx.x;
  for (int e = tid; e < 512; e += 256) {
    float v;
    if (e < 32)       v = c0[a * 32  + e];
    else if (e < 128) v = c1[a * 96  + (e - 32)];
    else if (e < 288) v = c2[a * 160 + (e - 128)];
    else              v = c3[a * 224 + (e - 288)];
    cs[e] = v;
  }
  __syncthreads();
  const float cg[4]  = {1.0f, 0.5773502691896258f, 0.4472135954999579f, 0.3779644730092272f};
  const int  off[4]  = {0, 32, 128, 288};
  const int  nm[4]   = {1, 3, 5, 7};
#pragma unroll
  for (int it = 0; it < 2; ++it) {
    int cc = tid + it * 256;          // chunk id in [0,512)
    int l = cc >> 7;
    int rem = cc & 127;
    int q = rem >> 2, rc = (rem & 3) * 8;
    const float* base = cs + off[l];
    float s[8] = {0.f, 0.f, 0.f, 0.f, 0.f, 0.f, 0.f, 0.f};
    for (int m = 0; m < nm[l]; ++m) {
      float bq = base[m * 32 + q];                       // wave-broadcast
      float4 v0 = *reinterpret_cast<const float4*>(&base[m * 32 + rc]);
      float4 v1 = *reinterpret_cast<const float4*>(&base[m * 32 + rc + 4]);
      s[0] += bq * v0.x; s[1] += bq * v0.y; s[2] += bq * v0.z; s[3] += bq * v0.w;
      s[4] += bq * v1.x; s[5] += bq * v1.y; s[6] += bq * v1.z; s[7] += bq * v1.w;
    }
    u16x8 o;
#pragma unroll
    for (int t = 0; t < 8; ++t) o[t] = f2h(s[t] * cg[l]);
    *reinterpret_cast<u16x8*>(&fh[(size_t)a * NFEAT + cc * 8]) = o;
  }
}

// ---------------- Kernel A2: W0 [p][k][n] fp32 -> W0t [p][n][k] fp16 --------
__global__ __launch_bounds__(256) void w0cvt_kernel(
    const float* __restrict__ W0, ushort* __restrict__ W0t) {
  __shared__ float t[32][33];
  int p = blockIdx.z;
  int kt = blockIdx.y * 32, nt = blockIdx.x * 32;
  int lx = threadIdx.x & 31, ly = threadIdx.x >> 5;
  const float* src = W0 + (size_t)p * NFEAT * HID;
#pragma unroll
  for (int i = 0; i < 4; ++i) {
    int k = kt + ly + i * 8;
    t[ly + i * 8][lx] = src[(size_t)k * HID + nt + lx];
  }
  __syncthreads();
  ushort* dst = W0t + (size_t)p * HID * NFEAT;
#pragma unroll
  for (int i = 0; i < 4; ++i) {
    int n = nt + ly + i * 8;
    dst[(size_t)n * NFEAT + kt + lx] = f2h(t[lx][ly + i * 8]);
  }
}

// ---------------- Kernel A3: W1 [p][k][n] fp32 -> W1t [p][n][k] fp16 --------
__global__ __launch_bounds__(256) void w1cvt_kernel(
    const float* __restrict__ W1, ushort* __restrict__ W1t) {
  __shared__ float t[32][33];
  int p = blockIdx.z;
  int kt = blockIdx.y * 32, nt = blockIdx.x * 32;
  int lx = threadIdx.x & 31, ly = threadIdx.x >> 5;
  const float* src = W1 + (size_t)p * HID * HID;
#pragma unroll
  for (int i = 0; i < 4; ++i) {
    int k = kt + ly + i * 8;
    t[ly + i * 8][lx] = src[(size_t)k * HID + nt + lx];
  }
  __syncthreads();
  ushort* dst = W1t + (size_t)p * HID * HID;
#pragma unroll
  for (int i = 0; i < 4; ++i) {
    int n = nt + ly + i * 8;
    dst[(size_t)n * HID + kt + lx] = f2h(t[lx][ly + i * 8]);
  }
}

// ---------------- Kernel B: fp16 MFMA GEMM0, BK=32 ------------------------
// LDS: 64 physical rows x 128B. Physical row pr, chunk pc holds logical
// (m_half = lg>>2, kc = lg&3) of m-row pr + 64*m_half, where lg = pc^(pr&7).
// 128B rows span all 32 banks; 8-chunk XOR -> conflict-free b128 reads.
// Block remap: xcd = linear&7 owns m-tiles {xcd, xcd+8, ...} so the 8 n-tiles
// of one m-tile share that XCD's L2 copy of A.
__global__ __launch_bounds__(256) void gemm0_mfma(
    const ushort* __restrict__ fh, const ushort* __restrict__ W0t,
    const float* __restrict__ combW, const int* __restrict__ species,
    ushort* __restrict__ h0f) {
  __shared__ ushort As[64 * 64];   // 8KB
  __shared__ ushort Bs[64 * 64];   // 8KB
  int tid = threadIdx.x;
  int linear = blockIdx.y * 8 + blockIdx.x;
  int xc = linear & 7, sq = linear >> 3;
  int bm = ((sq >> 3) * 8 + xc) * 128;   // m-tile
  int bn = (sq & 7) * 128;               // n-tile
  int wid = tid >> 6, lane = tid & 63;
  int wm = (wid >> 1) * 64, wn = (wid & 1) * 64;
  int mh = wid >> 1, nh = wid & 1;

  // staging decode (loop-invariant): thread -> physical (pr, pc), pr2 = pr+32
  int pr = tid >> 3, pc = tid & 7;
  int lg = pc ^ (pr & 7);
  int mhalf = lg >> 2, kc = lg & 3;
  const ushort* gaA1 = fh  + ((size_t)(bm + pr + 64 * mhalf) * NFEAT + kc * 8);
  const ushort* gaA2 = gaA1 + (size_t)32 * NFEAT;
  const ushort* gaB1 = W0t + ((size_t)(bn + pr + 64 * mhalf) * NFEAT + kc * 8);
  const ushort* gaB2 = gaB1 + (size_t)32 * NFEAT;
  ushort* lA = As + tid * 8;             // = pr*128B + pc*16B
  ushort* lB = Bs + tid * 8;

  f32x4 acc[4][4];
#pragma unroll
  for (int i = 0; i < 4; ++i)
#pragma unroll
    for (int j = 0; j < 4; ++j) acc[i][j] = (f32x4){0.f, 0.f, 0.f, 0.f};

  int mrow = lane & 15;
  int h7 = mrow & 7;
  int qv = lane >> 4;                    // logical k-chunk (0..3)
  int pcA = ((mh << 2) | qv) ^ h7;       // physical chunk for A reads
  int pcB = ((nh << 2) | qv) ^ h7;       // physical chunk for B reads

  for (int k0 = 0; k0 < NFEAT; k0 += 32) {
    glds16(gaA1 + k0, lA);
    glds16(gaA2 + k0, lA + 2048);
    glds16(gaB1 + k0, lB);
    glds16(gaB2 + k0, lB + 2048);
    __syncthreads();

    f16x8 af[4], bf[4];
#pragma unroll
    for (int i = 0; i < 4; ++i) {
      af[i] = *reinterpret_cast<const f16x8*>(&As[(i * 16 + mrow) * 64 + pcA * 8]);
      bf[i] = *reinterpret_cast<const f16x8*>(&Bs[(i * 16 + mrow) * 64 + pcB * 8]);
    }
#pragma unroll
    for (int i = 0; i < 4; ++i)
#pragma unroll
      for (int j = 0; j < 4; ++j)
        acc[i][j] = __builtin_amdgcn_mfma_f32_16x16x32_f16(af[i], bf[j], acc[i][j], 0, 0, 0);
    __syncthreads();
  }

  // epilogue: D row = (lane>>4)*4 + r, col = lane&15; pad rows -> 0
  int p = bn >> 8;
  int col = lane & 15, rbase = (lane >> 4) * 4;
#pragma unroll
  for (int i = 0; i < 4; ++i) {
#pragma unroll
    for (int r = 0; r < 4; ++r) {
      int m = bm + wm + i * 16 + rbase + r;
      bool live = (m < N_ATOMS);
      float pw = live ? combW[p * NS + species[m]] : 0.f;
#pragma unroll
      for (int j = 0; j < 4; ++j) {
        int n = bn + wn + j * 16 + col;
        float v = live ? silu(pw * acc[i][j][r]) : 0.f;
        h0f[(size_t)m * 1024 + n] = f2h(v);
      }
    }
  }
}

// ---------------- Kernel C: layer-1 fp16 MFMA GEMM + silu, swizzled --------
__global__ __launch_bounds__(256) void mlp1_mfma(
    const ushort* __restrict__ h0f, const ushort* __restrict__ W1t,
    ushort* __restrict__ h1f) {
  __shared__ ushort As[128 * 32];
  __shared__ ushort Bs[128 * 32];
  int tid = threadIdx.x;
  int bm = blockIdx.y * 128;
  int bn = blockIdx.x * 128;   // global n in [0,1024)
  int p  = bn >> 8;
  int wid = tid >> 6, lane = tid & 63;
  int wm = (wid >> 1) * 64, wn = (wid & 1) * 64;

  int row0 = tid >> 2;
  int kidx = (tid & 3) ^ (row0 & 3);
  const ushort* ga = h0f + ((size_t)(bm + row0) * 1024 + p * 256 + kidx * 8);
  const ushort* gb = W1t + ((size_t)(bn + row0) * 256 + kidx * 8);
  ushort* lA = As + tid * 8;
  ushort* lB = Bs + tid * 8;
  const size_t halfA = (size_t)64 * 1024;
  const size_t halfB = (size_t)64 * 256;

  f32x4 acc[4][4];
#pragma unroll
  for (int i = 0; i < 4; ++i)
#pragma unroll
    for (int j = 0; j < 4; ++j) acc[i][j] = (f32x4){0.f, 0.f, 0.f, 0.f};

  int mrow = lane & 15;
  int key = mrow & 3;
  int qv = lane >> 4;

  for (int k0 = 0; k0 < 256; k0 += 32) {
    glds16(ga + k0,         lA);
    glds16(ga + k0 + halfA, lA + 2048);
    glds16(gb + k0,         lB);
    glds16(gb + k0 + halfB, lB + 2048);
    __syncthreads();

    int sw = (qv ^ key) * 8;
    f16x8 af[4], bf[4];
#pragma unroll
    for (int i = 0; i < 4; ++i) {
      af[i] = *reinterpret_cast<const f16x8*>(&As[(wm + i * 16 + mrow) * 32 + sw]);
      bf[i] = *reinterpret_cast<const f16x8*>(&Bs[(wn + i * 16 + mrow) * 32 + sw]);
    }
#pragma unroll
    for (int i = 0; i < 4; ++i)
#pragma unroll
      for (int j = 0; j < 4; ++j)
        acc[i][j] = __builtin_amdgcn_mfma_f32_16x16x32_f16(af[i], bf[j], acc[i][j], 0, 0, 0);
    __syncthreads();
  }

  int col = lane & 15, rbase = (lane >> 4) * 4;
#pragma unroll
  for (int i = 0; i < 4; ++i) {
#pragma unroll
    for (int r = 0; r < 4; ++r) {
      int m = bm + wm + i * 16 + rbase + r;
      if (m >= N_ATOMS) continue;
#pragma unroll
      for (int j = 0; j < 4; ++j) {
        int n = bn + wn + j * 16 + col;
        h1f[(size_t)m * 1024 + n] = f2h(silu(acc[i][j][r]));
      }
    }
  }
}

// ---------------- Kernel D: layer-2 dot + segment-sum ----------------
__global__ __launch_bounds__(256) void final_kernel(
    const ushort* __restrict__ h1f, const float* __restrict__ W2,
    const int* __restrict__ sid, float* __restrict__ out) {
  int wv = threadIdx.x >> 6, lane = threadIdx.x & 63;
  int a = blockIdx.x * 4 + wv;
  if (a >= N_ATOMS) return;
  const ushort* hrow = h1f + (size_t)a * 1024 + lane * 16;
  f16x8 h1 = *reinterpret_cast<const f16x8*>(hrow);
  f16x8 h2 = *reinterpret_cast<const f16x8*>(hrow + 8);
  const float* w2 = W2 + lane * 16;
  float v = 0.f;
#pragma unroll
  for (int t = 0; t < 8; ++t) v += (float)h1[t] * w2[t];
#pragma unroll
  for (int t = 0; t < 8; ++t) v += (float)h2[t] * w2[8 + t];
#pragma unroll
  for (int off = 32; off > 0; off >>= 1) v += __shfl_xor(v, off, 64);
  if (lane == 0) atomicAdd(&out[sid[a]], v);
}

extern "C" void kernel_launch(void* const* d_in, const int* in_sizes, int n_in,
                              void* d_out, int out_size, void* d_ws, size_t ws_size,
                              hipStream_t stream) {
  const float* c0      = (const float*)d_in[0];
  const float* c1      = (const float*)d_in[1];
  const float* c2      = (const float*)d_in[2];
  const float* c3      = (const float*)d_in[3];
  const int*   species = (const int*)d_in[4];
  const int*   sid     = (const int*)d_in[5];
  const float* combW   = (const float*)d_in[6];
  const float* W0      = (const float*)d_in[7];
  const float* W1      = (const float*)d_in[8];
  const float* W2      = (const float*)d_in[9];
  float*       out     = (float*)d_out;

  // ws: fh 83.9MB | W0t 8.4MB | W1t 0.5MB | h0f 21MB | h1f 21MB = ~135MB
  ushort* fh  = (ushort*)d_ws;
  ushort* W0t = fh  + (size_t)APAD * NFEAT;
  ushort* W1t = W0t + (size_t)NP * HID * NFEAT;
  ushort* h0f = W1t + (size_t)NP * HID * HID;
  ushort* h1f = h0f + (size_t)APAD * 1024;

  (void)hipMemsetAsync(out, 0, (size_t)out_size * sizeof(float), stream);
  (void)hipMemsetAsync(fh + (size_t)N_ATOMS * NFEAT, 0,
                       (size_t)(APAD - N_ATOMS) * NFEAT * sizeof(ushort), stream);

  feat_kernel<<<N_ATOMS, 256, 0, stream>>>(c0, c1, c2, c3, fh);

  dim3 gw(HID / 32, NFEAT / 32, NP);
  w0cvt_kernel<<<gw, 256, 0, stream>>>(W0, W0t);
  dim3 gw1(HID / 32, HID / 32, NP);
  w1cvt_kernel<<<gw1, 256, 0, stream>>>(W1, W1t);

  dim3 g2(8, APAD / 128);   // 8 n-tiles x 80 remapped slots
  gemm0_mfma<<<g2, 256, 0, stream>>>(fh, W0t, combW, species, h0f);

  dim3 g3(8, 79);           // covers rows 0..10111 >= N_ATOMS
  mlp1_mfma<<<g3, 256, 0, stream>>>(h0f, W1t, h1f);

  final_kernel<<<2500, 256, 0, stream>>>(h1f, W2, sid, out);
}